// Round 12
// baseline (159.867 us; speedup 1.0000x reference)
//
#include <hip/hip_runtime.h>
#include <cstdint>

// Problem constants (static shapes from reference)
#define NBI 128
#define NBC 128
#define NR_ 36
#define NW_ 50
#define EMB_ 1024
#define MTOT (NBI * NR_)   // 4608
#define NTOT (NBC * NW_)   // 6400
#define OUTN (NBI * NBC * NW_)  // 819200

// Compaction geometry
#define BM 144             // rows per M block (whole images packed, cap 144)
#define MAXMB 44           // worst-case M blocks (each closed block holds >=109 rows)
#define ASLOTS (MAXMB * 144)   // 6336 A slot-rows
// meta layout (int32 offsets into meta[]):
#define MT_NMB 0           // n_mblks
#define MT_NNT 1           // n_ntiles
#define MT_NCOL 2          // ncols
#define MT_IMGF 16         // img_first[45]
#define MT_LO 64           // lo_in_block[128]
#define MT_ROWSRC 256      // rowsrc[ASLOTS]
#define MT_COLSRC (256 + ASLOTS)  // colsrc[6400]
#define META_INTS (MT_COLSRC + NTOT)

typedef _Float16 f16;
typedef _Float16 f16x8 __attribute__((ext_vector_type(8)));
typedef float f32x4 __attribute__((ext_vector_type(4)));

// ---------------- planning: pack whole images into 144-row blocks; compact cols ----------------
__global__ void plan_kernel(const int* __restrict__ img_lens, const int* __restrict__ cap_lens,
                            int* __restrict__ meta) {
  __shared__ int s_imgf[45], s_lo[128], s_blk[128], s_capstart[128], s_scal[3];
  const int t = threadIdx.x;
  if (t == 0) {
    int nb = 0, used = 0;
    s_imgf[0] = 0;
    for (int i = 0; i < 128; ++i) {
      int len = img_lens[i];
      if (used + len > BM) { ++nb; s_imgf[nb] = i; used = 0; }
      s_blk[i] = nb; s_lo[i] = used; used += len;
    }
    ++nb; 
    for (int b = nb; b <= 44; ++b) s_imgf[b] = 128;
    s_scal[0] = nb;
    int nc = 0;
    for (int c = 0; c < 128; ++c) { s_capstart[c] = nc; nc += cap_lens[c]; }
    s_scal[1] = (nc + 127) >> 7;  // n_ntiles
    s_scal[2] = nc;
  }
  __syncthreads();
  if (t < 3) meta[MT_NMB + t] = s_scal[t];
  if (t < 45) meta[MT_IMGF + t] = s_imgf[t];
  if (t < 128) meta[MT_LO + t] = s_lo[t];
  for (int k = t; k < ASLOTS; k += 256) meta[MT_ROWSRC + k] = -1;
  for (int k = t; k < NTOT; k += 256) meta[MT_COLSRC + k] = -1;
  __syncthreads();
  if (t < 128) {
    int len = img_lens[t];
    int base = s_blk[t] * BM + s_lo[t];
    for (int r = 0; r < len; ++r) meta[MT_ROWSRC + base + r] = t * 36 + r;
    int cap = cap_lens[t];
    int cbase = s_capstart[t];
    for (int w = 0; w < cap; ++w) meta[MT_COLSRC + cbase + w] = t * 50 + w;
  }
}

// ---------------- prep: gathered f32->f16 conversion for A,B + (-1)-fill of invalid cols ----------------
__global__ void prep_kernel(const float* __restrict__ imgs, const float* __restrict__ caps,
                            const int* __restrict__ cap_lens, const int* __restrict__ meta,
                            f16* __restrict__ Af, f16* __restrict__ Bf, float* __restrict__ out) {
  int idx = blockIdx.x * 256 + threadIdx.x;
  const int nA = ASLOTS * 128;          // 811008 16B-units
  const int nB = NTOT * 128;            // 819200
  if (idx < nA) {
    int row = idx >> 7, u = idx & 127;
    int src = meta[MT_ROWSRC + row];
    union { f16 h[8]; uint4 q; } r;
    if (src >= 0) {
      const float4* s = (const float4*)(imgs + (size_t)src * 1024 + u * 8);
      float4 a = s[0], b = s[1];
      r.h[0] = (f16)a.x; r.h[1] = (f16)a.y; r.h[2] = (f16)a.z; r.h[3] = (f16)a.w;
      r.h[4] = (f16)b.x; r.h[5] = (f16)b.y; r.h[6] = (f16)b.z; r.h[7] = (f16)b.w;
    } else {
      r.q = uint4{0u, 0u, 0u, 0u};
    }
    ((uint4*)Af)[idx] = r.q;
  } else if (idx < nA + nB) {
    int k = idx - nA;
    int row = k >> 7, u = k & 127;
    int src = meta[MT_COLSRC + row];
    union { f16 h[8]; uint4 q; } r;
    if (src >= 0) {
      const float4* s = (const float4*)(caps + (size_t)src * 1024 + u * 8);
      float4 a = s[0], b = s[1];
      r.h[0] = (f16)a.x; r.h[1] = (f16)a.y; r.h[2] = (f16)a.z; r.h[3] = (f16)a.w;
      r.h[4] = (f16)b.x; r.h[5] = (f16)b.y; r.h[6] = (f16)b.z; r.h[7] = (f16)b.w;
    } else {
      r.q = uint4{0u, 0u, 0u, 0u};
    }
    ((uint4*)Bf)[idx - nA] = r.q;
  } else {
    int k = idx - nA - nB;
    if (k < OUTN) {
      int col = k % 6400;
      int c = col / 50, w = col - 50 * c;
      if (w >= cap_lens[c]) out[k] = -1.0f;   // invalid word -> -1 (disjoint from gemm stores)
    }
  }
}

// ---------------- fused GEMM + masked region-maxpool over compacted panels ----------------
// A slots [n_mblks*144 x 1024] f16 (whole images packed per 144-row block),
// B slots [n_ntiles*128 x 1024] f16 (valid (c,w) cols compacted). C = A*B^T,
// per-image masked max over the block's packed rows, direct final store.
// BK=64, 4 waves in 1Mx4N split: wave = 144x32 = acc[9][2] 16x16 tiles.
__launch_bounds__(256, 3)
__global__ void gemm_max_kernel(const f16* __restrict__ A, const f16* __restrict__ B,
                                const int* __restrict__ img_lens,
                                const int* __restrict__ meta,
                                float* __restrict__ out) {
  __shared__ unsigned char smem[34816];  // A 144x128B = 18KB @0, B 128x128B = 16KB @18432

  // XCD swizzle (2200 = 8*275, bijective) + supertile (5 supercols x (44bm x 10bn)).
  const int bx = blockIdx.x;
  const int L = (bx & 7) * 275 + (bx >> 3);
  const int sc = L / 440;
  const int rem = L - sc * 440;
  const int bm = rem % 44;
  const int bn = sc * 10 + rem / 44;

  const int n_mblks = meta[MT_NMB];
  const int n_ntiles = meta[MT_NNT];
  if (bm >= n_mblks || bn >= n_ntiles) return;   // uniform exit before any barrier

  const int t = threadIdx.x;
  const int lane = t & 63;
  const int wv = t >> 6;                     // wave 0..3 -> cols [wv*32, wv*32+32)

  f32x4 acc[9][2] = {};

  const char* Ab = (const char*)A + (size_t)(bm * BM) * 2048;
  const char* Bb = (const char*)B + (size_t)(bn * 128) * 2048;

  // Staging: A = 144 rows x 8 units = 1152, B = 128 x 8 = 1024 16B-units.
  // LDS dest LINEAR (wave-uniform base + lane*16); XOR swizzle (row&7)<<4 on the
  // GLOBAL source and again on the ds_read side (rule #21, same involution).
  int sdstA[5], sgofA[5];
#pragma unroll
  for (int j = 0; j < 5; ++j) {
    int u = t + 256 * j;                  // j==4 used only when t<128
    int row = u >> 3;
    int phys = (u & 7) * 16;
    int logical = phys ^ ((row & 7) << 4);
    sdstA[j] = u * 16;
    sgofA[j] = row * 2048 + logical;
  }
  int sdstB[4], sgofB[4];
#pragma unroll
  for (int j = 0; j < 4; ++j) {
    int u = t + 256 * j;
    int row = u >> 3;
    int phys = (u & 7) * 16;
    int logical = phys ^ ((row & 7) << 4);
    sdstB[j] = 18432 + u * 16;
    sgofB[j] = row * 2048 + logical;
  }

  for (int ck = 0; ck < 16; ++ck) {
    const int k0b = ck * 128;
#pragma unroll
    for (int j = 0; j < 4; ++j) {
      __builtin_amdgcn_global_load_lds(
          (const __attribute__((address_space(1))) void*)(Ab + (size_t)sgofA[j] + k0b),
          (__attribute__((address_space(3))) void*)(smem + sdstA[j]), 16, 0, 0);
    }
    if (t < 128) {  // waves 0,1: rows 128..143 (wave-uniform branch)
      __builtin_amdgcn_global_load_lds(
          (const __attribute__((address_space(1))) void*)(Ab + (size_t)sgofA[4] + k0b),
          (__attribute__((address_space(3))) void*)(smem + sdstA[4]), 16, 0, 0);
    }
#pragma unroll
    for (int j = 0; j < 4; ++j) {
      __builtin_amdgcn_global_load_lds(
          (const __attribute__((address_space(1))) void*)(Bb + (size_t)sgofB[j] + k0b),
          (__attribute__((address_space(3))) void*)(smem + sdstB[j]), 16, 0, 0);
    }
    __syncthreads();  // vmcnt(0) drained before barrier: staged data visible

#pragma unroll
    for (int kk = 0; kk < 2; ++kk) {
      f16x8 af[9], bf[2];
#pragma unroll
      for (int mt = 0; mt < 9; ++mt) {
        int row = mt * 16 + (lane & 15);
        int col = (kk * 64 + (lane >> 4) * 16) ^ ((row & 7) << 4);
        af[mt] = *(const f16x8*)(smem + row * 128 + col);
      }
#pragma unroll
      for (int nt = 0; nt < 2; ++nt) {
        int row = wv * 32 + nt * 16 + (lane & 15);
        int col = (kk * 64 + (lane >> 4) * 16) ^ ((row & 7) << 4);
        bf[nt] = *(const f16x8*)(smem + 18432 + row * 128 + col);
      }
#pragma unroll
      for (int mt = 0; mt < 9; ++mt)
#pragma unroll
        for (int nt = 0; nt < 2; ++nt)
          acc[mt][nt] = __builtin_amdgcn_mfma_f32_16x16x32_f16(af[mt], bf[nt], acc[mt][nt], 0, 0, 0);
    }
    __syncthreads();
  }

  // ---------------- epilogue: per-image masked max + direct store ----------------
  // D layout (m89): local row = mt*16 + (lane>>4)*4 + r4, col = lane&15.
  const int q4 = ((lane >> 4) << 2);
  const int cg0 = bn * 128 + wv * 32 + (lane & 15);
  const int cg1 = cg0 + 16;
  int oc0 = -1, oc1 = -1;
  if (lane < 16) { oc0 = meta[MT_COLSRC + cg0]; oc1 = meta[MT_COLSRC + cg1]; }

  const int jf = meta[MT_IMGF + bm];
  const int jl = meta[MT_IMGF + bm + 1];
  for (int j = jf; j < jl; ++j) {
    const int len = img_lens[j];              // 1..36
    const int lo = meta[MT_LO + j];
    const int hi = lo + len;
    float v0 = -3.0e38f, v1 = -3.0e38f;
#pragma unroll
    for (int mt = 0; mt < 9; ++mt) {
#pragma unroll
      for (int r4 = 0; r4 < 4; ++r4) {
        int row = mt * 16 + q4 + r4;
        if (row >= lo && row < hi) {
          v0 = fmaxf(v0, acc[mt][0][r4]);
          v1 = fmaxf(v1, acc[mt][1][r4]);
        }
      }
    }
    v0 = fmaxf(v0, __shfl_xor(v0, 16)); v0 = fmaxf(v0, __shfl_xor(v0, 32));
    v1 = fmaxf(v1, __shfl_xor(v1, 16)); v1 = fmaxf(v1, __shfl_xor(v1, 32));
    if (len < NR_) { v0 = fmaxf(v0, -1.0f); v1 = fmaxf(v1, -1.0f); }  // -1 fill participates
    if (lane < 16) {
      if (oc0 >= 0) out[(size_t)j * 6400 + oc0] = v0;
      if (oc1 >= 0) out[(size_t)j * 6400 + oc1] = v1;
    }
  }
}

extern "C" void kernel_launch(void* const* d_in, const int* in_sizes, int n_in,
                              void* d_out, int out_size, void* d_ws, size_t ws_size,
                              hipStream_t stream) {
  const float* imgs = (const float*)d_in[0];
  const float* caps = (const float*)d_in[1];
  const int* img_lens = (const int*)d_in[2];
  const int* cap_lens = (const int*)d_in[3];
  float* out = (float*)d_out;

  char* ws = (char*)d_ws;
  f16* Af = (f16*)ws;                                         // 6336*1024*2 = 12.98 MB
  f16* Bf = (f16*)(ws + (size_t)ASLOTS * EMB_ * 2);           // 6400*1024*2 = 13.11 MB
  int* meta = (int*)(ws + (size_t)ASLOTS * EMB_ * 2 + (size_t)NTOT * EMB_ * 2);  // ~52 KB

  const int nA = ASLOTS * 128;
  const int nB = NTOT * 128;
  const int nprep = nA + nB + OUTN;   // 2,449,408

  plan_kernel<<<1, 256, 0, stream>>>(img_lens, cap_lens, meta);
  prep_kernel<<<(nprep + 255) / 256, 256, 0, stream>>>(imgs, caps, cap_lens, meta, Af, Bf, out);
  gemm_max_kernel<<<MAXMB * 50, 256, 0, stream>>>(Af, Bf, img_lens, meta, out);
}

// Round 15
// 141.767 us; speedup vs baseline: 1.1277x; 1.1277x over previous
//
#include <hip/hip_runtime.h>
#include <cstdint>

// Problem constants (static shapes from reference)
#define NBI 128
#define NBC 128
#define NR_ 36
#define NW_ 50
#define EMB_ 1024
#define MTOT (NBI * NR_)   // 4608
#define NTOT (NBC * NW_)   // 6400
#define OUTN (NBI * NBC * NW_)  // 819200

// Compaction geometry
#define BM 144             // rows per M block (whole images packed, cap 144)
#define MAXMB 44           // worst-case M blocks (each closed block holds >=109 rows)
#define ASLOTS (MAXMB * 144)   // 6336 A slot-rows
// meta layout (int32 offsets into meta[]):
#define MT_NMB 0           // n_mblks
#define MT_NNT 1           // n_ntiles
#define MT_NCOL 2          // ncols
#define MT_IMGF 16         // img_first[45]
#define MT_LO 64           // lo_in_block[128]
#define MT_ROWSRC 256      // rowsrc[ASLOTS]
#define MT_COLSRC (256 + ASLOTS)  // colsrc[6400]

#define LDSBUF 34816       // one stage buffer: A 144x128B=18432 + B 128x128B=16384

typedef _Float16 f16;
typedef _Float16 f16x8 __attribute__((ext_vector_type(8)));
typedef float f32x4 __attribute__((ext_vector_type(4)));

// ---------------- planning: pack whole images into 144-row blocks; compact cols ----------------
__global__ void plan_kernel(const int* __restrict__ img_lens, const int* __restrict__ cap_lens,
                            int* __restrict__ meta) {
  __shared__ int s_imgf[45], s_lo[128], s_blk[128], s_capstart[128], s_scal[3];
  const int t = threadIdx.x;
  if (t == 0) {
    int nb = 0, used = 0;
    s_imgf[0] = 0;
    for (int i = 0; i < 128; ++i) {
      int len = img_lens[i];
      if (used + len > BM) { ++nb; s_imgf[nb] = i; used = 0; }
      s_blk[i] = nb; s_lo[i] = used; used += len;
    }
    ++nb;
    for (int b = nb; b <= 44; ++b) s_imgf[b] = 128;
    s_scal[0] = nb;
    int nc = 0;
    for (int c = 0; c < 128; ++c) { s_capstart[c] = nc; nc += cap_lens[c]; }
    s_scal[1] = (nc + 127) >> 7;  // n_ntiles
    s_scal[2] = nc;
  }
  __syncthreads();
  if (t < 3) meta[MT_NMB + t] = s_scal[t];
  if (t < 45) meta[MT_IMGF + t] = s_imgf[t];
  if (t < 128) meta[MT_LO + t] = s_lo[t];
  for (int k = t; k < ASLOTS; k += 256) meta[MT_ROWSRC + k] = -1;
  for (int k = t; k < NTOT; k += 256) meta[MT_COLSRC + k] = -1;
  __syncthreads();
  if (t < 128) {
    int len = img_lens[t];
    int base = s_blk[t] * BM + s_lo[t];
    for (int r = 0; r < len; ++r) meta[MT_ROWSRC + base + r] = t * 36 + r;
    int cap = cap_lens[t];
    int cbase = s_capstart[t];
    for (int w = 0; w < cap; ++w) meta[MT_COLSRC + cbase + w] = t * 50 + w;
  }
}

// ---------------- prep: gathered f32->f16 conversion for A,B + (-1)-fill of invalid cols ----------------
__global__ void prep_kernel(const float* __restrict__ imgs, const float* __restrict__ caps,
                            const int* __restrict__ cap_lens, const int* __restrict__ meta,
                            f16* __restrict__ Af, f16* __restrict__ Bf, float* __restrict__ out) {
  int idx = blockIdx.x * 256 + threadIdx.x;
  const int nA = ASLOTS * 128;          // 811008 16B-units
  const int nB = NTOT * 128;            // 819200
  if (idx < nA) {
    int row = idx >> 7, u = idx & 127;
    int src = meta[MT_ROWSRC + row];
    union { f16 h[8]; uint4 q; } r;
    if (src >= 0) {
      const float4* s = (const float4*)(imgs + (size_t)src * 1024 + u * 8);
      float4 a = s[0], b = s[1];
      r.h[0] = (f16)a.x; r.h[1] = (f16)a.y; r.h[2] = (f16)a.z; r.h[3] = (f16)a.w;
      r.h[4] = (f16)b.x; r.h[5] = (f16)b.y; r.h[6] = (f16)b.z; r.h[7] = (f16)b.w;
    } else {
      r.q = uint4{0u, 0u, 0u, 0u};
    }
    ((uint4*)Af)[idx] = r.q;
  } else if (idx < nA + nB) {
    int k = idx - nA;
    int row = k >> 7, u = k & 127;
    int src = meta[MT_COLSRC + row];
    union { f16 h[8]; uint4 q; } r;
    if (src >= 0) {
      const float4* s = (const float4*)(caps + (size_t)src * 1024 + u * 8);
      float4 a = s[0], b = s[1];
      r.h[0] = (f16)a.x; r.h[1] = (f16)a.y; r.h[2] = (f16)a.z; r.h[3] = (f16)a.w;
      r.h[4] = (f16)b.x; r.h[5] = (f16)b.y; r.h[6] = (f16)b.z; r.h[7] = (f16)b.w;
    } else {
      r.q = uint4{0u, 0u, 0u, 0u};
    }
    ((uint4*)Bf)[idx - nA] = r.q;
  } else {
    int k = idx - nA - nB;
    if (k < OUTN) {
      int col = k % 6400;
      int c = col / 50, w = col - 50 * c;
      if (w >= cap_lens[c]) out[k] = -1.0f;   // invalid word -> -1 (disjoint from gemm stores)
    }
  }
}

// ---------------- fused GEMM + masked region-maxpool, balanced + double-buffered ----------------
// Active rectangle n_mblks x n_ntiles (~19 x 26). Block bx < nact maps via the
// m204 bijective XCD swizzle (hardware: bx%8 -> XCD) so every XCD gets an equal
// contiguous chunk of column-major (bm fast) logical order => B-tile L2 reuse.
// 2-phase LDS double-buffer (T3 minimum recipe): STAGE(next) issued BEFORE
// compute(cur); __syncthreads' vmcnt(0) then waits on loads a full compute
// phase old -> staging latency hidden. LDS = 2 x 34816 = 68 KB STATIC
// (within gfx950's 160KB group segment; 2 blocks/CU x 68KB = 136KB <= 160KB).
#define STAGE(buf, ckk) do {                                                            \
    const int sb_ = (buf) * LDSBUF;                                                     \
    const int kb_ = (ckk) * 128;                                                        \
    _Pragma("unroll")                                                                   \
    for (int j = 0; j < 4; ++j)                                                         \
      __builtin_amdgcn_global_load_lds(                                                 \
          (const __attribute__((address_space(1))) void*)(Ab + (size_t)sgofA[j] + kb_), \
          (__attribute__((address_space(3))) void*)(smem + sb_ + sdstA[j]), 16, 0, 0);  \
    if (t < 128)                                                                        \
      __builtin_amdgcn_global_load_lds(                                                 \
          (const __attribute__((address_space(1))) void*)(Ab + (size_t)sgofA[4] + kb_), \
          (__attribute__((address_space(3))) void*)(smem + sb_ + sdstA[4]), 16, 0, 0);  \
    _Pragma("unroll")                                                                   \
    for (int j = 0; j < 4; ++j)                                                         \
      __builtin_amdgcn_global_load_lds(                                                 \
          (const __attribute__((address_space(1))) void*)(Bb + (size_t)sgofB[j] + kb_), \
          (__attribute__((address_space(3))) void*)(smem + sb_ + sdstB[j]), 16, 0, 0);  \
  } while (0)

#define COMPUTE(buf) do {                                                               \
    const int sb_ = (buf) * LDSBUF;                                                     \
    _Pragma("unroll")                                                                   \
    for (int kk = 0; kk < 2; ++kk) {                                                    \
      f16x8 af[9], bf[2];                                                               \
      _Pragma("unroll")                                                                 \
      for (int mt = 0; mt < 9; ++mt) {                                                  \
        int row = mt * 16 + (lane & 15);                                                \
        int col = (kk * 64 + (lane >> 4) * 16) ^ ((row & 7) << 4);                      \
        af[mt] = *(const f16x8*)(smem + sb_ + row * 128 + col);                         \
      }                                                                                 \
      _Pragma("unroll")                                                                 \
      for (int nt = 0; nt < 2; ++nt) {                                                  \
        int row = wv * 32 + nt * 16 + (lane & 15);                                      \
        int col = (kk * 64 + (lane >> 4) * 16) ^ ((row & 7) << 4);                      \
        bf[nt] = *(const f16x8*)(smem + sb_ + 18432 + row * 128 + col);                 \
      }                                                                                 \
      _Pragma("unroll")                                                                 \
      for (int mt = 0; mt < 9; ++mt)                                                    \
        _Pragma("unroll")                                                               \
        for (int nt = 0; nt < 2; ++nt)                                                  \
          acc[mt][nt] = __builtin_amdgcn_mfma_f32_16x16x32_f16(af[mt], bf[nt],          \
                                                               acc[mt][nt], 0, 0, 0);  \
    }                                                                                   \
  } while (0)

__launch_bounds__(256, 2)
__global__ void gemm_max_kernel(const f16* __restrict__ A, const f16* __restrict__ B,
                                const int* __restrict__ img_lens,
                                const int* __restrict__ meta,
                                float* __restrict__ out) {
  static __shared__ unsigned char smem[2 * LDSBUF];  // 69632 B static LDS

  const int n_mblks = meta[MT_NMB];
  const int n_ntiles = meta[MT_NNT];
  const int nact = n_mblks * n_ntiles;
  const int bx = blockIdx.x;
  if (bx >= nact) return;                    // uniform exit before any barrier

  // m204 bijective XCD chunking over the ACTIVE count (fixes round-12 imbalance)
  const int xcd = bx & 7, idx = bx >> 3;
  const int q = nact >> 3, r = nact & 7;
  const int L = (xcd < r ? xcd * (q + 1) : r * (q + 1) + (xcd - r) * q) + idx;
  const int bn = L / n_mblks;                // column-major: consecutive L share bn
  const int bm = L - bn * n_mblks;

  const int t = threadIdx.x;
  const int lane = t & 63;
  const int wv = t >> 6;                     // wave 0..3 -> cols [wv*32, wv*32+32)

  f32x4 acc[9][2] = {};

  const char* Ab = (const char*)A + (size_t)(bm * BM) * 2048;
  const char* Bb = (const char*)B + (size_t)(bn * 128) * 2048;

  // Staging: A = 144 rows x 8 units = 1152, B = 128 x 8 = 1024 16B-units.
  // LDS dest LINEAR (wave-uniform base + lane*16); XOR swizzle (row&7)<<4 on the
  // GLOBAL source and again on the ds_read side (rule #21, same involution).
  int sdstA[5], sgofA[5];
#pragma unroll
  for (int j = 0; j < 5; ++j) {
    int u = t + 256 * j;                  // j==4 used only when t<128
    int row = u >> 3;
    int phys = (u & 7) * 16;
    int logical = phys ^ ((row & 7) << 4);
    sdstA[j] = u * 16;
    sgofA[j] = row * 2048 + logical;
  }
  int sdstB[4], sgofB[4];
#pragma unroll
  for (int j = 0; j < 4; ++j) {
    int u = t + 256 * j;
    int row = u >> 3;
    int phys = (u & 7) * 16;
    int logical = phys ^ ((row & 7) << 4);
    sdstB[j] = 18432 + u * 16;
    sgofB[j] = row * 2048 + logical;
  }

  // -------- 2-phase pipelined K loop (16 chunks of BK=64) --------
  STAGE(0, 0);
  __syncthreads();                            // chunk 0 staged
  for (int ck = 0; ck < 15; ++ck) {
    STAGE((ck + 1) & 1, ck + 1);              // issue next-chunk loads (other buffer)
    COMPUTE(ck & 1);                          // ds_read + MFMA current buffer
    __syncthreads();                          // drains vmcnt(0): next chunk ready;
                                              // all waves done reading cur buffer
  }
  COMPUTE(1);                                 // chunk 15 (buffer 1), no prefetch

  // ---------------- epilogue: per-image masked max + direct store ----------------
  // D layout (m89): local row = mt*16 + (lane>>4)*4 + r4, col = lane&15.
  const int q4 = ((lane >> 4) << 2);
  const int cg0 = bn * 128 + wv * 32 + (lane & 15);
  const int cg1 = cg0 + 16;
  int oc0 = -1, oc1 = -1;
  if (lane < 16) { oc0 = meta[MT_COLSRC + cg0]; oc1 = meta[MT_COLSRC + cg1]; }

  const int jf = meta[MT_IMGF + bm];
  const int jl = meta[MT_IMGF + bm + 1];
  for (int j = jf; j < jl; ++j) {
    const int len = img_lens[j];              // 1..36
    const int lo = meta[MT_LO + j];
    const int hi = lo + len;
    float v0 = -3.0e38f, v1 = -3.0e38f;
#pragma unroll
    for (int mt = 0; mt < 9; ++mt) {
#pragma unroll
      for (int r4 = 0; r4 < 4; ++r4) {
        int row = mt * 16 + q4 + r4;
        if (row >= lo && row < hi) {
          v0 = fmaxf(v0, acc[mt][0][r4]);
          v1 = fmaxf(v1, acc[mt][1][r4]);
        }
      }
    }
    v0 = fmaxf(v0, __shfl_xor(v0, 16)); v0 = fmaxf(v0, __shfl_xor(v0, 32));
    v1 = fmaxf(v1, __shfl_xor(v1, 16)); v1 = fmaxf(v1, __shfl_xor(v1, 32));
    if (len < NR_) { v0 = fmaxf(v0, -1.0f); v1 = fmaxf(v1, -1.0f); }  // -1 fill participates
    if (lane < 16) {
      if (oc0 >= 0) out[(size_t)j * 6400 + oc0] = v0;
      if (oc1 >= 0) out[(size_t)j * 6400 + oc1] = v1;
    }
  }
}

extern "C" void kernel_launch(void* const* d_in, const int* in_sizes, int n_in,
                              void* d_out, int out_size, void* d_ws, size_t ws_size,
                              hipStream_t stream) {
  const float* imgs = (const float*)d_in[0];
  const float* caps = (const float*)d_in[1];
  const int* img_lens = (const int*)d_in[2];
  const int* cap_lens = (const int*)d_in[3];
  float* out = (float*)d_out;

  char* ws = (char*)d_ws;
  f16* Af = (f16*)ws;                                         // 6336*1024*2 = 12.98 MB
  f16* Bf = (f16*)(ws + (size_t)ASLOTS * EMB_ * 2);           // 6400*1024*2 = 13.11 MB
  int* meta = (int*)(ws + (size_t)ASLOTS * EMB_ * 2 + (size_t)NTOT * EMB_ * 2);  // ~52 KB

  const int nA = ASLOTS * 128;
  const int nB = NTOT * 128;
  const int nprep = nA + nB + OUTN;   // 2,449,408

  plan_kernel<<<1, 256, 0, stream>>>(img_lens, cap_lens, meta);
  prep_kernel<<<(nprep + 255) / 256, 256, 0, stream>>>(imgs, caps, cap_lens, meta, Af, Bf, out);
  gemm_max_kernel<<<MAXMB * 50, 256, 0, stream>>>(Af, Bf, img_lens, meta, out);
}